// Round 1
// 643.456 us; speedup vs baseline: 1.0403x; 1.0403x over previous
//
#include <hip/hip_runtime.h>
#include <math.h>

#define SMOOTHING 0.1f
#define EPSILON_F 1e-8f
#define LOG2E_F   1.44269504088896340736f
#define DEFER_THR 10.0f

typedef float vf4 __attribute__((ext_vector_type(4)));

__device__ __forceinline__ float fexp2(float x) { return __builtin_amdgcn_exp2f(x); }

// Non-temporal float4 load: logits are streamed exactly once — keep them out
// of L2 so the 128 KB weight array (reused by all 4096 blocks) stays resident.
__device__ __forceinline__ vf4 ntload4(const vf4* p) {
    return __builtin_nontemporal_load(p);
}

// Combine two (max, sumexp) states. S values are natural sum-exp relative to M.
__device__ __forceinline__ void osm_combine(float& m, float& s, float mo, float so) {
    float nm = fmaxf(m, mo);
    s = s * fexp2((m - nm) * LOG2E_F) + so * fexp2((mo - nm) * LOG2E_F);
    m = nm;
}

// Deferred-max online-softmax update over one float4 + weighted-dot accumulation.
// Steady state (no new max beyond threshold): 3 fmax + 1 cmp + 4 fma + 4 exp2
// + 4 add + 4 fma(wd) + 4 add(ws). No loop-carried rescale chain: S, wd, ws are
// plain accumulators; M/nMs are read-only except on the rare rescale branch.
// Values are bounded by e^DEFER_THR (e^10 ~ 2.2e4); S <= 4000 * 2.2e4 ~ 9e7,
// far inside fp32 range, and log(S) precision is unaffected (terms the deferred
// max "overweights" are mathematically that much larger).
__device__ __forceinline__ void osm_update4(float& M, float& nMs, float& S,
                                            vf4 v, vf4 w, float& wd, float& ws) {
    float c01 = fmaxf(v.x, v.y);
    float c23 = fmaxf(v.z, v.w);
    float cm  = fmaxf(c01, c23);
    if (__builtin_expect(cm > M + DEFER_THR, 0)) {
        // rare: rescale S to the new reference max.
        // first trigger: M = -1e30 -> (M-cm)*LOG2E finite-huge-negative -> exp2 = 0, S stays 0.
        S *= fexp2((M - cm) * LOG2E_F);
        M = cm;
        nMs = -M * LOG2E_F;
    }
    float e0 = fexp2(fmaf(v.x, LOG2E_F, nMs));
    float e1 = fexp2(fmaf(v.y, LOG2E_F, nMs));
    float e2 = fexp2(fmaf(v.z, LOG2E_F, nMs));
    float e3 = fexp2(fmaf(v.w, LOG2E_F, nMs));
    S += (e0 + e1) + (e2 + e3);
    wd = fmaf(w.x, v.x, wd);
    wd = fmaf(w.y, v.y, wd);
    wd = fmaf(w.z, v.z, wd);
    wd = fmaf(w.w, v.w, wd);
    ws += (w.x + w.y) + (w.z + w.w);
}

// One row (C fp32 logits) per 256-thread block. Two independent chains
// (front/back half of the row) for ILP; all four float4 loads issued
// back-to-back each iteration to keep bytes in flight.
__global__ __launch_bounds__(256) void Seq2SeqLoss_row_kernel(
    const float* __restrict__ logits,
    const int*   __restrict__ gold,
    const int*   __restrict__ mask,
    const float* __restrict__ weight,
    float*       __restrict__ row_loss,
    int C)
{
    const int row = blockIdx.x;
    const int tid = threadIdx.x;
    const float* __restrict__ x = logits + (size_t)row * (size_t)C;

    // Epilogue inputs: loop-independent, issue the (dependent) gather now so
    // its latency hides under the row scan.
    const int   g  = gold[row];
    const int   mk = mask[row];
    const float xg = x[g];
    const float wg = weight[g];

    const int C4   = C >> 2;        // float4 count (C % 4 == 0)
    const int half = C4 >> 1;       // two chains: [0,half) and [half,2*half)
    const vf4* __restrict__ x4  = (const vf4*)x;
    const vf4* __restrict__ x4h = x4 + half;
    const vf4* __restrict__ w4  = (const vf4*)weight;
    const vf4* __restrict__ w4h = w4 + half;

    float M0 = -1e30f, nMs0 = 0.f, S0 = 0.f;
    float M1 = -1e30f, nMs1 = 0.f, S1 = 0.f;
    float wd = 0.f, wsum = 0.f;

    for (int i = tid; i < half; i += 256) {
        vf4 a  = ntload4(x4  + i);
        vf4 b  = ntload4(x4h + i);
        vf4 wa = w4[i];
        vf4 wb = w4h[i];
        osm_update4(M0, nMs0, S0, a, wa, wd, wsum);
        osm_update4(M1, nMs1, S1, b, wb, wd, wsum);
    }
    // tail if C4 is odd (not hit for C=32000)
    for (int i = (half << 1) + tid; i < C4; i += 256) {
        vf4 a  = ntload4(x4 + i);
        vf4 wa = w4[i];
        osm_update4(M0, nMs0, S0, a, wa, wd, wsum);
    }

    osm_combine(M0, S0, M1, S1);
    float M = M0, S = S0;

    // wave(64)-level reduce
    #pragma unroll
    for (int off = 32; off >= 1; off >>= 1) {
        float Mo = __shfl_down(M, off);
        float So = __shfl_down(S, off);
        wd   += __shfl_down(wd, off);
        wsum += __shfl_down(wsum, off);
        osm_combine(M, S, Mo, So);
    }

    // cross-wave (4 waves) via LDS
    __shared__ float shM[4], shS[4], shWD[4], shWS[4];
    const int wave = tid >> 6;
    if ((tid & 63) == 0) { shM[wave] = M; shS[wave] = S; shWD[wave] = wd; shWS[wave] = wsum; }
    __syncthreads();

    if (tid == 0) {
        #pragma unroll
        for (int w = 1; w < 4; ++w) {
            osm_combine(M, S, shM[w], shS[w]);
            wd   += shWD[w];
            wsum += shWS[w];
        }
        float logZ = M + logf(S);

        const float uniform    = SMOOTHING / (float)(C - 1);
        const float confidence = 1.0f - SMOOTHING;

        float total    = logZ * wsum - wd;        // sum_c w_c * (logZ - x_c)
        float gold_nll = logZ - xg;
        float loss = uniform * total + (confidence - uniform) * wg * gold_nll;

        loss *= (mk != 0) ? 1.0f : 0.0f;
        row_loss[row] = loss;
    }
}

// Single-block deterministic finalize: out = sum(row_loss) / (sum(mask) + eps)
__global__ __launch_bounds__(1024) void Seq2SeqLoss_finalize_kernel(
    const float* __restrict__ row_loss,
    const int*   __restrict__ mask,
    float*       __restrict__ out,
    int N)
{
    const int tid = threadIdx.x;
    float acc = 0.f, cnt = 0.f;
    for (int i = tid; i < N; i += 1024) {
        acc += row_loss[i];
        cnt += (mask[i] != 0) ? 1.0f : 0.0f;
    }
    #pragma unroll
    for (int off = 32; off >= 1; off >>= 1) {
        acc += __shfl_down(acc, off);
        cnt += __shfl_down(cnt, off);
    }
    __shared__ float shA[16], shC[16];
    const int wave = tid >> 6;
    if ((tid & 63) == 0) { shA[wave] = acc; shC[wave] = cnt; }
    __syncthreads();
    if (tid == 0) {
        #pragma unroll
        for (int w = 1; w < 16; ++w) { acc += shA[w]; cnt += shC[w]; }
        out[0] = acc / (cnt + EPSILON_F);
    }
}

extern "C" void kernel_launch(void* const* d_in, const int* in_sizes, int n_in,
                              void* d_out, int out_size, void* d_ws, size_t ws_size,
                              hipStream_t stream) {
    const float* logits = (const float*)d_in[0];   // [B,S,C] fp32
    const int*   gold   = (const int*)d_in[1];     // [B,S]   (int64 in ref -> int32 here)
    const int*   mask   = (const int*)d_in[2];     // [B,S]   (bool in ref -> int32 here)
    const float* weight = (const float*)d_in[3];   // [C]     fp32

    const int N = in_sizes[1];   // B*S = 4096 rows
    const int C = in_sizes[3];   // 32000 classes

    float* row_loss = (float*)d_ws;  // N floats = 16 KB scratch

    Seq2SeqLoss_row_kernel<<<N, 256, 0, stream>>>(logits, gold, mask, weight, row_loss, C);
    Seq2SeqLoss_finalize_kernel<<<1, 1024, 0, stream>>>(row_loss, mask, (float*)d_out, N);
}